// Round 14
// baseline (448.092 us; speedup 1.0000x reference)
//
#include <hip/hip_runtime.h>
#include <math.h>

#define BN 4
#define CC 32
#define HH 64
#define WW 64
#define DD 288          // C*K*K
#define EE 144
#define NTOK 4096
#define SCALE_F 0.2357022603955158f           // 18^-0.5
#define QSCALE  0.3401074286f                 // SCALE_F * log2(e)
#define QKST 384        // qkT row stride: 8 heads*24 Q | 8 heads*24 K
#define MQKV 528        // padded QKV GEMM M: 192 Q + 192 K + 144 V

typedef __bf16 bf16x8 __attribute__((ext_vector_type(8)));
typedef float floatx4 __attribute__((ext_vector_type(4)));
typedef unsigned short u16x8 __attribute__((ext_vector_type(8)));

__device__ __forceinline__ unsigned short f2bf(float x) {
    unsigned int u = __float_as_uint(x);
    u += 0x7fffu + ((u >> 16) & 1u);          // RNE
    return (unsigned short)(u >> 16);
}
__device__ __forceinline__ float bf2f(unsigned short s) {
    return __uint_as_float(((unsigned int)s) << 16);
}
// pack hi16(a), hi16(b) -> (b_hi<<16)|a_hi  — single v_perm_b32
__device__ __forceinline__ unsigned int pack_bf_trunc(float a, float b) {
    return __builtin_amdgcn_perm(__float_as_uint(b), __float_as_uint(a), 0x07060302u);
}

// ---------------- merged setup: LN-folded weights + bf16 weight conversion ----------------
// blocks 0..2: precompute wg/wgsum/wbeta for layer l=blockIdx.x (144 active threads)
// blocks 3..1532: weight conversion
__global__ __launch_bounds__(256) void setup_k(
    const float* __restrict__ wr0, const float* __restrict__ br0,
    const float* __restrict__ wr1, const float* __restrict__ br1,
    const float* __restrict__ wr2, const float* __restrict__ br2,
    const float* __restrict__ g,  const float* __restrict__ lb,
    const float* __restrict__ wqkv0, const float* __restrict__ wqkv1, const float* __restrict__ wqkv2,
    const float* __restrict__ we0,   const float* __restrict__ we1,   const float* __restrict__ we2,
    unsigned short* __restrict__ wg_bf, float* __restrict__ wgsum, float* __restrict__ wbeta,
    unsigned short* __restrict__ wqkv_bf, unsigned short* __restrict__ we_bf)
{
    int blk = blockIdx.x;
    int tid = threadIdx.x;
    if (blk < 3) {
        if (tid < 144) {
            int l = blk, e = tid;
            const float* wr = (l == 0) ? wr0 : ((l == 1) ? wr1 : wr2);
            const float* br = (l == 0) ? br0 : ((l == 1) ? br1 : br2);
            float sg = 0.f, sb = 0.f;
            for (int d = 0; d < DD; ++d) {
                float w = wr[e * DD + d];
                float wgv = w * g[d];
                wg_bf[((size_t)l * EE + e) * DD + d] = f2bf(wgv);
                sg += wgv;
                sb += w * lb[d];
            }
            wgsum[l * EE + e] = sg;
            wbeta[l * EE + e] = sb + br[e];
        }
        return;
    }
    int idx = (blk - 3) * 256 + tid;
    const int T1 = 3 * MQKV * 160;
    const int T2 = 3 * 288 * 160;
    if (idx < T1) {
        int l = idx / (MQKV * 160), r = idx % (MQKV * 160);
        int m = r / 160, k = r % 160;
        const float* w = (l == 0) ? wqkv0 : ((l == 1) ? wqkv1 : wqkv2);
        float v = 0.f;
        if (k < 144) {
            if (m < 192) {
                int h = m / 24, j = m % 24;
                if (j < 18) v = w[(h * 18 + j) * 144 + k] * QSCALE;
            } else if (m < 384) {
                int mm = m - 192, h = mm / 24, j = mm % 24;
                if (j < 18) v = w[(144 + h * 18 + j) * 144 + k];
            } else {
                v = w[(288 + (m - 384)) * 144 + k];
            }
        }
        wqkv_bf[idx] = f2bf(v);
    } else if (idx < T1 + T2) {
        int j = idx - T1;
        int l = j / (288 * 160), r = j % (288 * 160);
        int m = r / 160, k = r % 160;
        const float* w = (l == 0) ? we0 : ((l == 1) ? we1 : we2);
        we_bf[j] = (k < 144) ? f2bf(w[m * 144 + k]) : 0;
    }
}

// ---------------- unfold + LN stats -> bf16 token-major only ----------------
__global__ __launch_bounds__(256) void unfold_k(const float* __restrict__ t,
    unsigned short* __restrict__ colsT,
    float* __restrict__ mu, float* __restrict__ rstd)
{
    __shared__ float red1[4][64], red2[4][64];
    int tid = threadIdx.x;
    int lane = tid & 63, cpart = tid >> 6;
    int b = blockIdx.x >> 6, nc = blockIdx.x & 63;
    int n = nc * 64 + lane;
    int h = n >> 6, w = n & 63;
    const float* tb = t + (size_t)b * CC * HH * WW;
    unsigned short loc[72];
    float s1 = 0.f, s2 = 0.f;
    #pragma unroll
    for (int c8 = 0; c8 < 8; ++c8) {
        int c = cpart * 8 + c8;
        const float* tc = tb + (size_t)c * 4096;
        #pragma unroll
        for (int i = 0; i < 3; ++i) {
            int hr = h + i - 1;
            bool rok = ((unsigned)hr < 64u);
            #pragma unroll
            for (int j = 0; j < 3; ++j) {
                int wc = w + j - 1;
                bool ok = rok && ((unsigned)wc < 64u);
                float v = ok ? tc[hr * 64 + wc] : 0.f;
                loc[c8 * 9 + i * 3 + j] = f2bf(v);
                s1 += v;
                s2 = fmaf(v, v, s2);
            }
        }
    }
    unsigned short* ct = colsT + ((size_t)b * NTOK + n) * 288 + cpart * 72;
    #pragma unroll
    for (int u = 0; u < 9; ++u)
        *(u16x8*)&ct[u * 8] = *(const u16x8*)&loc[u * 8];
    red1[cpart][lane] = s1;
    red2[cpart][lane] = s2;
    __syncthreads();
    if (tid < 64) {
        float a = red1[0][tid] + red1[1][tid] + red1[2][tid] + red1[3][tid];
        float q = red2[0][tid] + red2[1][tid] + red2[2][tid] + red2[3][tid];
        float m = a * (1.f / 288.f);
        float var = q * (1.f / 288.f) - m * m;
        int nn = nc * 64 + tid;
        mu[b * NTOK + nn] = m;
        rstd[b * NTOK + nn] = rsqrtf(var + 1e-5f);
    }
}

// ---------------- LDS-free bf16 MFMA GEMM (frozen): C[m][n] = sum_k A[m][k]*Bt[n][k] ----------------
template<int K, int MODE, int NYB>
__global__ __launch_bounds__(256) void mgemm_k(
    const unsigned short* __restrict__ A, const unsigned short* __restrict__ Bt, int BST,
    unsigned short* __restrict__ Ct, unsigned short* __restrict__ Cv,
    const float* __restrict__ mu, const float* __restrict__ rstd,
    const float* __restrict__ wgsum, const float* __restrict__ wbeta,
    const float* __restrict__ bias)
{
    constexpr int NT = 64;
    __shared__ unsigned short Ts[64 * 56];         // 7 KB epilogue scratch (>= 48*72)
    int flat = blockIdx.x;
    int g  = (flat / (8 * NYB)) * 8 + (flat & 7);  // B-tile group (fixed XCD = g%8)
    int jm = (flat % (8 * NYB)) >> 3;              // m-block within group
    int n0 = (g & 63) * NT;                        // g % (NTOK/NT)
    int bI = g >> 6;
    int m0 = jm * 48;
    int tid = threadIdx.x;
    int wv = tid >> 6, lane = tid & 63;
    int l15 = lane & 15, l4 = lane >> 4;

    const unsigned short* Arow = A + (size_t)(m0 + l15) * K + l4 * 8;
    const unsigned short* Brow = Bt + ((size_t)bI * NTOK + n0 + wv * 16 + l15) * BST + l4 * 8;

    floatx4 acc[3];
    acc[0] = acc[1] = acc[2] = (floatx4){0.f, 0.f, 0.f, 0.f};

    #pragma unroll
    for (int ks = 0; ks < K / 32; ++ks) {
        bf16x8 bfr = *(const bf16x8*)(Brow + ks * 32);
        #pragma unroll
        for (int mi = 0; mi < 3; ++mi) {
            bf16x8 af = *(const bf16x8*)(Arow + (size_t)mi * 16 * K + ks * 32);
            acc[mi] = __builtin_amdgcn_mfma_f32_16x16x32_bf16(af, bfr, acc[mi], 0, 0, 0);
        }
    }

    int n_l = wv * 16 + l15;                        // token col within tile (0..63)

    if (MODE == 2) {
        #pragma unroll
        for (int mi = 0; mi < 3; ++mi)
            #pragma unroll
            for (int r = 0; r < 4; ++r) {
                int m_l = mi * 16 + l4 * 4 + r;
                Ts[m_l * 72 + n_l] = f2bf(acc[mi][r] + bias[m0 + m_l]);
            }
        __syncthreads();
        for (int u = tid; u < 48 * 8; u += 256) {
            int row = u >> 3, seg = u & 7;
            unsigned short* dst = Ct + ((size_t)bI * DD + m0 + row) * NTOK + n0 + seg * 8;
            *(u16x8*)dst = *(const u16x8*)&Ts[row * 72 + seg * 8];
        }
    } else {
        bool vpath = (MODE == 0) && (m0 >= 384);
        float muv = 0.f, rsv = 0.f;
        if (MODE == 1) {
            int n_g = n0 + n_l;
            muv = mu[bI * NTOK + n_g];
            rsv = rstd[bI * NTOK + n_g];
        }
        #pragma unroll
        for (int mi = 0; mi < 3; ++mi)
            #pragma unroll
            for (int r = 0; r < 4; ++r) {
                int m_l = mi * 16 + l4 * 4 + r;
                float v = acc[mi][r];
                if (MODE == 1) v = rsv * (v - muv * wgsum[m0 + m_l]) + wbeta[m0 + m_l];
                if (!vpath) Ts[n_l * 56 + m_l] = f2bf(v);
                else        Ts[m_l * 72 + n_l] = f2bf(v);
            }
        __syncthreads();
        if (!vpath) {
            const int CTS = (MODE == 1) ? 160 : QKST;
            if (tid < 128) {
                int row = tid >> 1, half = tid & 1;
                unsigned short* dst = Ct + ((size_t)bI * NTOK + n0 + row) * CTS + m0 + half * 24;
                const unsigned short* src = &Ts[row * 56 + half * 24];
                #pragma unroll
                for (int u = 0; u < 3; ++u)
                    *(u16x8*)&dst[u * 8] = *(const u16x8*)&src[u * 8];
                if (MODE == 1 && m0 == 96) {
                    u16x8 z = (u16x8)0;
                    *(u16x8*)(Ct + ((size_t)bI * NTOK + n0 + row) * 160 + 144 + half * 8) = z;
                }
            }
        } else {
            for (int u = tid; u < 48 * 8; u += 256) {
                int row = u >> 3, seg = u & 7;
                unsigned short* dst = Cv + ((size_t)bI * EE + (m0 - 384) + row) * NTOK + n0 + seg * 8;
                *(u16x8*)dst = *(const u16x8*)&Ts[row * 72 + seg * 8];
            }
        }
    }
}

// ---------------- MFMA bf16 attention, register-prefetch pipeline, slim LDS ----------------
// Ks stride 24 (d-pad 24..31 synthesized via l4==3 mask, like Q); Vs only real rows
// 0..17 (rows 18..30 = 0, row 31 = 1.0 synthesized per-lane). LDS 37.4 -> ~28.8 KB
// => 5 blocks/CU (was 4). Numerics bit-identical to R11.
__global__ __launch_bounds__(256) void attn_k2(const unsigned short* __restrict__ qkT,
                                               const unsigned short* __restrict__ vF,
                                               unsigned short* __restrict__ oT)
{
    __shared__ unsigned short Ks[128 * 24 + 32];  // [tok][24], +slack for masked l4==3 reads
    __shared__ unsigned short Vs[18 * 136];       // [d<18][tok pad 136]
    __shared__ unsigned short Ps[4 * 32 * 72];    // per-wave [q][tok(64) pad 72]

    int blk = blockIdx.x;
    int bhs = blk & 127;
    int qc  = blk >> 7;
    int b = bhs >> 5, h = (bhs >> 2) & 7, s = bhs & 3;
    int tid  = threadIdx.x;
    int wv   = tid >> 6;
    int lane = tid & 63;
    int l15 = lane & 15, l4 = lane >> 4;
    int q0 = qc * 128;
    int tokbase = s * 1024;

    const unsigned short* qkb = qkT + (size_t)b * NTOK * QKST;

    bf16x8 qf[2];
    #pragma unroll
    for (int ni = 0; ni < 2; ++ni) {
        u16x8 raw = *(const u16x8*)(qkb + (size_t)(tokbase + q0 + wv * 32 + ni * 16 + l15) * QKST
                                    + 24 * h + l4 * 8);
        if (l4 == 3) raw = (u16x8)0;
        qf[ni] = *(bf16x8*)&raw;
    }

    floatx4 oacc[2][2];
    #pragma unroll
    for (int i = 0; i < 2; ++i)
        #pragma unroll
        for (int j = 0; j < 2; ++j)
            oacc[i][j] = (floatx4){0.f, 0.f, 0.f, 0.f};

    unsigned short* Pw = &Ps[wv * 32 * 72];

    // V row source for vf[1]: row = 16+l15 clamped to 17; lanes l15>=2 get synthesized pad
    int vrow1 = (l15 < 2) ? (16 + l15) : 17;
    u16x8 vpad1 = (u16x8)((l15 == 15) ? (unsigned short)0x3F80 : (unsigned short)0);

    u16x8 preg[3];
    int vb = tid - 128;
    bool v3 = (vb < 32);
    if (tid < 128) {
        const unsigned short* src = qkb + (size_t)(tokbase + tid) * QKST + 192 + 24 * h;
        preg[0] = *(const u16x8*)&src[0];
        preg[1] = *(const u16x8*)&src[8];
        preg[2] = *(const u16x8*)&src[16];
    } else {
        const unsigned short* vbb = vF + (size_t)b * EE * NTOK + tokbase;
        #pragma unroll
        for (int u = 0; u < 3; ++u) {
            int idx = vb + u * 128;
            if (u < 2 || v3) {
                int d = idx >> 4, seg = idx & 15;
                preg[u] = *(const u16x8*)(vbb + (size_t)(h * 18 + d) * NTOK + seg * 8);
            }
        }
    }

    for (int c0 = 0; c0 < 1024; c0 += 128) {
        __syncthreads();
        if (tid < 128) {
            unsigned short* dk = &Ks[tid * 24];
            *(u16x8*)&dk[0]  = preg[0];
            *(u16x8*)&dk[8]  = preg[1];
            *(u16x8*)&dk[16] = preg[2];
        } else {
            #pragma unroll
            for (int u = 0; u < 3; ++u) {
                int idx = vb + u * 128;
                if (u < 2 || v3) {
                    int d = idx >> 4, seg = idx & 15;      // d < 18
                    *(u16x8*)&Vs[d * 136 + seg * 8] = preg[u];
                }
            }
        }
        int cn = c0 + 128;
        if (cn < 1024) {
            if (tid < 128) {
                const unsigned short* src = qkb + (size_t)(tokbase + cn + tid) * QKST + 192 + 24 * h;
                preg[0] = *(const u16x8*)&src[0];
                preg[1] = *(const u16x8*)&src[8];
                preg[2] = *(const u16x8*)&src[16];
            } else {
                const unsigned short* vbb = vF + (size_t)b * EE * NTOK + tokbase + cn;
                #pragma unroll
                for (int u = 0; u < 3; ++u) {
                    int idx = vb + u * 128;
                    if (u < 2 || v3) {
                        int d = idx >> 4, seg = idx & 15;
                        preg[u] = *(const u16x8*)(vbb + (size_t)(h * 18 + d) * NTOK + seg * 8);
                    }
                }
            }
        }
        __syncthreads();

        #pragma unroll
        for (int sub = 0; sub < 2; ++sub) {
            bf16x8 kf[4];
            #pragma unroll
            for (int mi = 0; mi < 4; ++mi) {
                u16x8 raw = *(const u16x8*)&Ks[(sub * 64 + mi * 16 + l15) * 24 + l4 * 8];
                if (l4 == 3) raw = (u16x8)0;               // d-pad 24..31
                kf[mi] = *(bf16x8*)&raw;
            }

            floatx4 sacc[4][2];
            #pragma unroll
            for (int mi = 0; mi < 4; ++mi)
                #pragma unroll
                for (int ni = 0; ni < 2; ++ni) {
                    floatx4 z = (floatx4){0.f, 0.f, 0.f, 0.f};
                    sacc[mi][ni] = __builtin_amdgcn_mfma_f32_16x16x32_bf16(kf[mi], qf[ni], z, 0, 0, 0);
                }

            #pragma unroll
            for (int mi = 0; mi < 4; ++mi)
                #pragma unroll
                for (int ni = 0; ni < 2; ++ni) {
                    int ql   = ni * 16 + l15;
                    int tokb = mi * 16 + l4 * 4;
                    unsigned int lo = pack_bf_trunc(exp2f(sacc[mi][ni][0]), exp2f(sacc[mi][ni][1]));
                    unsigned int hi = pack_bf_trunc(exp2f(sacc[mi][ni][2]), exp2f(sacc[mi][ni][3]));
                    uint2 pk = make_uint2(lo, hi);
                    *(uint2*)&Pw[ql * 72 + tokb] = pk;
                }

            #pragma unroll
            for (int ks = 0; ks < 2; ++ks) {
                bf16x8 pf[2], vf[2];
                pf[0] = *(const bf16x8*)&Pw[(     l15) * 72 + ks * 32 + l4 * 8];
                pf[1] = *(const bf16x8*)&Pw[(16 + l15) * 72 + ks * 32 + l4 * 8];
                // vf[0]: d = l15 (0..15, all real rows)
                vf[0] = *(const bf16x8*)&Vs[l15 * 136 + sub * 64 + ks * 32 + l4 * 8];
                // vf[1]: d = 16+l15 -> rows 16,17 real; 18..30 zero; 31 = 1.0 (l-sum row)
                u16x8 r1 = *(const u16x8*)&Vs[vrow1 * 136 + sub * 64 + ks * 32 + l4 * 8];
                if (l15 >= 2) r1 = vpad1;
                vf[1] = *(bf16x8*)&r1;
                #pragma unroll
                for (int mi = 0; mi < 2; ++mi)
                    #pragma unroll
                    for (int nd = 0; nd < 2; ++nd)
                        oacc[mi][nd] = __builtin_amdgcn_mfma_f32_16x16x32_bf16(pf[mi], vf[nd], oacc[mi][nd], 0, 0, 0);
            }
        }
    }

    float* fO = (float*)Pw;
    #pragma unroll
    for (int mi = 0; mi < 2; ++mi)
        #pragma unroll
        for (int r = 0; r < 4; ++r) {
            float lsum = __shfl(oacc[mi][1][r], (lane & 48) | 15, 64);
            float inv  = 1.f / lsum;
            int ql = mi * 16 + l4 * 4 + r;
            fO[ql * 33 + l15] = oacc[mi][0][r] * inv;
            if (l15 < 2) fO[ql * 33 + 16 + l15] = oacc[mi][1][r] * inv;
        }

    {
        int q = lane & 31, dh = lane >> 5;
        size_t rowi = (size_t)b * NTOK + tokbase + q0 + wv * 32 + q;
        unsigned short* orow = oT + rowi * 160 + h * 18;
        for (int i = dh; i < 9; i += 2) {
            float a  = fO[q * 33 + 2 * i];
            float bb = fO[q * 33 + 2 * i + 1];
            *(unsigned int*)&orow[2 * i] = (unsigned)f2bf(a) | ((unsigned)f2bf(bb) << 16);
        }
        if (h == 7) {
            u16x8 z = (u16x8)0;
            *(u16x8*)(oT + rowi * 160 + 144 + dh * 8) = z;
        }
    }
}

// ---------------- fold (bf16 cols) + masked residual ----------------
__global__ __launch_bounds__(256) void fold_k(const unsigned short* __restrict__ cols,
                                              const float* __restrict__ tprev,
                                              float* __restrict__ t)
{
    int idx = blockIdx.x * 256 + threadIdx.x;
    int w = idx & 63;
    int h = (idx >> 6) & 63;
    int c = (idx >> 12) & 31;
    int b = idx >> 17;
    const unsigned short* cb = cols + (size_t)b * DD * NTOK + (size_t)c * 9 * NTOK;
    float sum = 0.f;
    #pragma unroll
    for (int i = 0; i < 3; ++i) {
        int hs = h + 1 - i;
        if ((unsigned)hs < 64u) {
            #pragma unroll
            for (int j = 0; j < 3; ++j) {
                int ws_ = w + 1 - j;
                if ((unsigned)ws_ < 64u)
                    sum += bf2f(cb[(size_t)(i * 3 + j) * NTOK + hs * 64 + ws_]);
            }
        }
    }
    int ch = (h == 0 || h == 63) ? 2 : 3;
    int cw_ = (w == 0 || w == 63) ? 2 : 3;
    t[idx] = sum + (float)(ch * cw_) * tprev[idx];
}

// ---------------- conv3x3 + ELU + residual, 4-pixel register strips ----------------
__global__ __launch_bounds__(256) void conv_k(const float* __restrict__ t,
    const float* __restrict__ cw, const float* __restrict__ cbias,
    const float* __restrict__ x, float* __restrict__ out)
{
    __shared__ float wsh[CC * 9];
    int blk = blockIdx.x;
    int band = blk & 3, co = (blk >> 2) & 31, b = blk >> 7;
    int tid = threadIdx.x;
    for (int u = tid; u < CC * 9; u += 256) wsh[u] = cw[co * CC * 9 + u];
    __syncthreads();
    int h = band * 16 + (tid >> 4);
    int w0 = (tid & 15) << 2;
    const float* tb = t + (size_t)b * CC * 4096;
    float bias = cbias[co];
    float a0 = bias, a1 = bias, a2 = bias, a3 = bias;
    for (int ci = 0; ci < CC; ++ci) {
        const float* tc = tb + (size_t)ci * 4096;
        const float* wr = &wsh[ci * 9];
        #pragma unroll
        for (int i = 0; i < 3; ++i) {
            int hr = h + i - 1;
            if ((unsigned)hr < 64u) {
                const float* row = tc + hr * 64;
                float vl = (w0 > 0)  ? row[w0 - 1] : 0.f;
                float4 c4 = *(const float4*)&row[w0];
                float vr = (w0 < 60) ? row[w0 + 4] : 0.f;
                float wj0 = wr[i * 3], wj1 = wr[i * 3 + 1], wj2 = wr[i * 3 + 2];
                a0 = fmaf(wj0, vl,   a0); a0 = fmaf(wj1, c4.x, a0); a0 = fmaf(wj2, c4.y, a0);
                a1 = fmaf(wj0, c4.x, a1); a1 = fmaf(wj1, c4.y, a1); a1 = fmaf(wj2, c4.z, a1);
                a2 = fmaf(wj0, c4.y, a2); a2 = fmaf(wj1, c4.z, a2); a2 = fmaf(wj2, c4.w, a2);
                a3 = fmaf(wj0, c4.z, a3); a3 = fmaf(wj1, c4.w, a3); a3 = fmaf(wj2, vr,   a3);
            }
        }
    }
    size_t oidx = ((size_t)(b * CC + co) * 4096) + h * 64 + w0;
    float4 xin = *(const float4*)&x[oidx];
    float4 o;
    o.x = xin.x + ((a0 > 0.f) ? a0 : (__expf(a0) - 1.f));
    o.y = xin.y + ((a1 > 0.f) ? a1 : (__expf(a1) - 1.f));
    o.z = xin.z + ((a2 > 0.f) ? a2 : (__expf(a2) - 1.f));
    o.w = xin.w + ((a3 > 0.f) ? a3 : (__expf(a3) - 1.f));
    *(float4*)&out[oidx] = o;
}

extern "C" void kernel_launch(void* const* d_in, const int* in_sizes, int n_in,
                              void* d_out, int out_size, void* d_ws, size_t ws_size,
                              hipStream_t stream)
{
    const float* x    = (const float*)d_in[0];
    const float* ln_g = (const float*)d_in[1];
    const float* ln_b = (const float*)d_in[2];
    const float* cw   = (const float*)d_in[3];
    const float* cb   = (const float*)d_in[4];
    const float* wr[3]   = {(const float*)d_in[5],  (const float*)d_in[10], (const float*)d_in[15]};
    const float* br[3]   = {(const float*)d_in[6],  (const float*)d_in[11], (const float*)d_in[16]};
    const float* wqkv[3] = {(const float*)d_in[7],  (const float*)d_in[12], (const float*)d_in[17]};
    const float* we[3]   = {(const float*)d_in[8],  (const float*)d_in[13], (const float*)d_in[18]};
    const float* be[3]   = {(const float*)d_in[9],  (const float*)d_in[14], (const float*)d_in[19]};
    float* out = (float*)d_out;

    char* p = (char*)d_ws;
    unsigned short* cols_bf = (unsigned short*)p; p += (size_t)BN * DD * NTOK * 2; // 9.4 MB (emha out, bf16)
    unsigned short* colsT = (unsigned short*)p; p += (size_t)BN * NTOK * 288 * 2;  // 9.4 MB
    unsigned short* oT = colsT;           // alias: disjoint lifetimes
    unsigned short* xrT   = (unsigned short*)p; p += (size_t)BN * NTOK * 160 * 2;  // 5.2 MB
    unsigned short* qkT   = (unsigned short*)p; p += (size_t)BN * NTOK * QKST * 2; // 12.6 MB
    unsigned short* vF    = (unsigned short*)p; p += (size_t)BN * EE * NTOK * 2;   // 4.7 MB
    float* mu   = (float*)p;              p += (size_t)BN * NTOK * 4;
    float* rstd = (float*)p;              p += (size_t)BN * NTOK * 4;
    float* tA   = (float*)p;              p += (size_t)BN * CC * HH * WW * 4;
    float* tB   = (float*)p;              p += (size_t)BN * CC * HH * WW * 4;
    unsigned short* wg_bf   = (unsigned short*)p; p += (size_t)3 * EE * DD * 2;
    unsigned short* wqkv_bf = (unsigned short*)p; p += (size_t)3 * MQKV * 160 * 2;
    unsigned short* we_bf   = (unsigned short*)p; p += (size_t)3 * DD * 160 * 2;
    float* wgsum = (float*)p;             p += 3 * EE * 4;
    float* wbeta = (float*)p;             p += 3 * EE * 4;
    (void)in_sizes; (void)n_in; (void)out_size; (void)ws_size;

    setup_k<<<1533, 256, 0, stream>>>(wr[0], br[0], wr[1], br[1], wr[2], br[2], ln_g, ln_b,
                                      wqkv[0], wqkv[1], wqkv[2], we[0], we[1], we[2],
                                      wg_bf, wgsum, wbeta, wqkv_bf, we_bf);

    const float* tin = x;
    float* touts[3] = {tA, tB, tA};
    for (int l = 0; l < 3; ++l) {
        unfold_k<<<256, 256, 0, stream>>>(tin, colsT, mu, rstd);
        // gemm1: K=288, M=144 (NYB=3)  -> grid 768
        mgemm_k<288, 1, 3><<<768, 256, 0, stream>>>(
            wg_bf + (size_t)l * EE * DD, colsT, 288, xrT, nullptr,
            mu, rstd, wgsum + l * EE, wbeta + l * EE, nullptr);
        // gemm2: K=160, M=528 (NYB=11) -> grid 2816
        mgemm_k<160, 0, 11><<<2816, 256, 0, stream>>>(
            wqkv_bf + (size_t)l * MQKV * 160, xrT, 160, qkT, vF,
            nullptr, nullptr, nullptr, nullptr, nullptr);
        attn_k2<<<1024, 256, 0, stream>>>(qkT, vF, oT);
        // gemm3: K=160, M=288 (NYB=6)  -> grid 1536
        mgemm_k<160, 2, 6><<<1536, 256, 0, stream>>>(
            we_bf + (size_t)l * DD * 160, oT, 160, cols_bf, nullptr,
            nullptr, nullptr, nullptr, nullptr, be[l]);
        fold_k<<<2048, 256, 0, stream>>>(cols_bf, tin, touts[l]);
        tin = touts[l];
    }
    conv_k<<<512, 256, 0, stream>>>(tA, cw, cb, x, out);
}

// Round 15
// 442.856 us; speedup vs baseline: 1.0118x; 1.0118x over previous
//
#include <hip/hip_runtime.h>
#include <math.h>

#define BN 4
#define CC 32
#define HH 64
#define WW 64
#define DD 288          // C*K*K
#define EE 144
#define NTOK 4096
#define SCALE_F 0.2357022603955158f           // 18^-0.5
#define QSCALE  0.3401074286f                 // SCALE_F * log2(e)
#define QKST 384        // qkT row stride: 8 heads*24 Q | 8 heads*24 K
#define MQKV 528        // padded QKV GEMM M: 192 Q + 192 K + 144 V

typedef __bf16 bf16x8 __attribute__((ext_vector_type(8)));
typedef float floatx4 __attribute__((ext_vector_type(4)));
typedef unsigned short u16x8 __attribute__((ext_vector_type(8)));

__device__ __forceinline__ unsigned short f2bf(float x) {
    unsigned int u = __float_as_uint(x);
    u += 0x7fffu + ((u >> 16) & 1u);          // RNE
    return (unsigned short)(u >> 16);
}
__device__ __forceinline__ float bf2f(unsigned short s) {
    return __uint_as_float(((unsigned int)s) << 16);
}
// pack hi16(a), hi16(b) -> (b_hi<<16)|a_hi  — single v_perm_b32
__device__ __forceinline__ unsigned int pack_bf_trunc(float a, float b) {
    return __builtin_amdgcn_perm(__float_as_uint(b), __float_as_uint(a), 0x07060302u);
}

// ---------------- merged setup: LN-folded weights + bf16 weight conversion ----------------
// blocks 0..2: precompute wg/wgsum/wbeta for layer l=blockIdx.x (144 active threads,
// runs in parallel with the 1530 conversion blocks -> hides the serial 288-loop)
__global__ __launch_bounds__(256) void setup_k(
    const float* __restrict__ wr0, const float* __restrict__ br0,
    const float* __restrict__ wr1, const float* __restrict__ br1,
    const float* __restrict__ wr2, const float* __restrict__ br2,
    const float* __restrict__ g,  const float* __restrict__ lb,
    const float* __restrict__ wqkv0, const float* __restrict__ wqkv1, const float* __restrict__ wqkv2,
    const float* __restrict__ we0,   const float* __restrict__ we1,   const float* __restrict__ we2,
    unsigned short* __restrict__ wg_bf, float* __restrict__ wgsum, float* __restrict__ wbeta,
    unsigned short* __restrict__ wqkv_bf, unsigned short* __restrict__ we_bf)
{
    int blk = blockIdx.x;
    int tid = threadIdx.x;
    if (blk < 3) {
        if (tid < 144) {
            int l = blk, e = tid;
            const float* wr = (l == 0) ? wr0 : ((l == 1) ? wr1 : wr2);
            const float* br = (l == 0) ? br0 : ((l == 1) ? br1 : br2);
            float sg = 0.f, sb = 0.f;
            for (int d = 0; d < DD; ++d) {
                float w = wr[e * DD + d];
                float wgv = w * g[d];
                wg_bf[((size_t)l * EE + e) * DD + d] = f2bf(wgv);
                sg += wgv;
                sb += w * lb[d];
            }
            wgsum[l * EE + e] = sg;
            wbeta[l * EE + e] = sb + br[e];
        }
        return;
    }
    int idx = (blk - 3) * 256 + tid;
    const int T1 = 3 * MQKV * 160;
    const int T2 = 3 * 288 * 160;
    if (idx < T1) {
        int l = idx / (MQKV * 160), r = idx % (MQKV * 160);
        int m = r / 160, k = r % 160;
        const float* w = (l == 0) ? wqkv0 : ((l == 1) ? wqkv1 : wqkv2);
        float v = 0.f;
        if (k < 144) {
            if (m < 192) {
                int h = m / 24, j = m % 24;
                if (j < 18) v = w[(h * 18 + j) * 144 + k] * QSCALE;
            } else if (m < 384) {
                int mm = m - 192, h = mm / 24, j = mm % 24;
                if (j < 18) v = w[(144 + h * 18 + j) * 144 + k];
            } else {
                v = w[(288 + (m - 384)) * 144 + k];
            }
        }
        wqkv_bf[idx] = f2bf(v);
    } else if (idx < T1 + T2) {
        int j = idx - T1;
        int l = j / (288 * 160), r = j % (288 * 160);
        int m = r / 160, k = r % 160;
        const float* w = (l == 0) ? we0 : ((l == 1) ? we1 : we2);
        we_bf[j] = (k < 144) ? f2bf(w[m * 144 + k]) : 0;
    }
}

// ---------------- unfold + LN stats -> bf16 token-major only ----------------
__global__ __launch_bounds__(256) void unfold_k(const float* __restrict__ t,
    unsigned short* __restrict__ colsT,
    float* __restrict__ mu, float* __restrict__ rstd)
{
    __shared__ float red1[4][64], red2[4][64];
    int tid = threadIdx.x;
    int lane = tid & 63, cpart = tid >> 6;
    int b = blockIdx.x >> 6, nc = blockIdx.x & 63;
    int n = nc * 64 + lane;
    int h = n >> 6, w = n & 63;
    const float* tb = t + (size_t)b * CC * HH * WW;
    unsigned short loc[72];
    float s1 = 0.f, s2 = 0.f;
    #pragma unroll
    for (int c8 = 0; c8 < 8; ++c8) {
        int c = cpart * 8 + c8;
        const float* tc = tb + (size_t)c * 4096;
        #pragma unroll
        for (int i = 0; i < 3; ++i) {
            int hr = h + i - 1;
            bool rok = ((unsigned)hr < 64u);
            #pragma unroll
            for (int j = 0; j < 3; ++j) {
                int wc = w + j - 1;
                bool ok = rok && ((unsigned)wc < 64u);
                float v = ok ? tc[hr * 64 + wc] : 0.f;
                loc[c8 * 9 + i * 3 + j] = f2bf(v);
                s1 += v;
                s2 = fmaf(v, v, s2);
            }
        }
    }
    unsigned short* ct = colsT + ((size_t)b * NTOK + n) * 288 + cpart * 72;
    #pragma unroll
    for (int u = 0; u < 9; ++u)
        *(u16x8*)&ct[u * 8] = *(const u16x8*)&loc[u * 8];
    red1[cpart][lane] = s1;
    red2[cpart][lane] = s2;
    __syncthreads();
    if (tid < 64) {
        float a = red1[0][tid] + red1[1][tid] + red1[2][tid] + red1[3][tid];
        float q = red2[0][tid] + red2[1][tid] + red2[2][tid] + red2[3][tid];
        float m = a * (1.f / 288.f);
        float var = q * (1.f / 288.f) - m * m;
        int nn = nc * 64 + tid;
        mu[b * NTOK + nn] = m;
        rstd[b * NTOK + nn] = rsqrtf(var + 1e-5f);
    }
}

// ---------------- LDS-free bf16 MFMA GEMM (frozen): C[m][n] = sum_k A[m][k]*Bt[n][k] ----------------
template<int K, int MODE, int NYB>
__global__ __launch_bounds__(256) void mgemm_k(
    const unsigned short* __restrict__ A, const unsigned short* __restrict__ Bt, int BST,
    unsigned short* __restrict__ Ct, unsigned short* __restrict__ Cv,
    const float* __restrict__ mu, const float* __restrict__ rstd,
    const float* __restrict__ wgsum, const float* __restrict__ wbeta,
    const float* __restrict__ bias)
{
    constexpr int NT = 64;
    __shared__ unsigned short Ts[64 * 56];         // 7 KB epilogue scratch (>= 48*72)
    int flat = blockIdx.x;
    int g  = (flat / (8 * NYB)) * 8 + (flat & 7);  // B-tile group (fixed XCD = g%8)
    int jm = (flat % (8 * NYB)) >> 3;              // m-block within group
    int n0 = (g & 63) * NT;                        // g % (NTOK/NT)
    int bI = g >> 6;
    int m0 = jm * 48;
    int tid = threadIdx.x;
    int wv = tid >> 6, lane = tid & 63;
    int l15 = lane & 15, l4 = lane >> 4;

    const unsigned short* Arow = A + (size_t)(m0 + l15) * K + l4 * 8;
    const unsigned short* Brow = Bt + ((size_t)bI * NTOK + n0 + wv * 16 + l15) * BST + l4 * 8;

    floatx4 acc[3];
    acc[0] = acc[1] = acc[2] = (floatx4){0.f, 0.f, 0.f, 0.f};

    #pragma unroll
    for (int ks = 0; ks < K / 32; ++ks) {
        bf16x8 bfr = *(const bf16x8*)(Brow + ks * 32);
        #pragma unroll
        for (int mi = 0; mi < 3; ++mi) {
            bf16x8 af = *(const bf16x8*)(Arow + (size_t)mi * 16 * K + ks * 32);
            acc[mi] = __builtin_amdgcn_mfma_f32_16x16x32_bf16(af, bfr, acc[mi], 0, 0, 0);
        }
    }

    int n_l = wv * 16 + l15;                        // token col within tile (0..63)

    if (MODE == 2) {
        #pragma unroll
        for (int mi = 0; mi < 3; ++mi)
            #pragma unroll
            for (int r = 0; r < 4; ++r) {
                int m_l = mi * 16 + l4 * 4 + r;
                Ts[m_l * 72 + n_l] = f2bf(acc[mi][r] + bias[m0 + m_l]);
            }
        __syncthreads();
        for (int u = tid; u < 48 * 8; u += 256) {
            int row = u >> 3, seg = u & 7;
            unsigned short* dst = Ct + ((size_t)bI * DD + m0 + row) * NTOK + n0 + seg * 8;
            *(u16x8*)dst = *(const u16x8*)&Ts[row * 72 + seg * 8];
        }
    } else {
        bool vpath = (MODE == 0) && (m0 >= 384);
        float muv = 0.f, rsv = 0.f;
        if (MODE == 1) {
            int n_g = n0 + n_l;
            muv = mu[bI * NTOK + n_g];
            rsv = rstd[bI * NTOK + n_g];
        }
        #pragma unroll
        for (int mi = 0; mi < 3; ++mi)
            #pragma unroll
            for (int r = 0; r < 4; ++r) {
                int m_l = mi * 16 + l4 * 4 + r;
                float v = acc[mi][r];
                if (MODE == 1) v = rsv * (v - muv * wgsum[m0 + m_l]) + wbeta[m0 + m_l];
                if (!vpath) Ts[n_l * 56 + m_l] = f2bf(v);
                else        Ts[m_l * 72 + n_l] = f2bf(v);
            }
        __syncthreads();
        if (!vpath) {
            const int CTS = (MODE == 1) ? 160 : QKST;
            if (tid < 128) {
                int row = tid >> 1, half = tid & 1;
                unsigned short* dst = Ct + ((size_t)bI * NTOK + n0 + row) * CTS + m0 + half * 24;
                const unsigned short* src = &Ts[row * 56 + half * 24];
                #pragma unroll
                for (int u = 0; u < 3; ++u)
                    *(u16x8*)&dst[u * 8] = *(const u16x8*)&src[u * 8];
                if (MODE == 1 && m0 == 96) {
                    u16x8 z = (u16x8)0;
                    *(u16x8*)(Ct + ((size_t)bI * NTOK + n0 + row) * 160 + 144 + half * 8) = z;
                }
            }
        } else {
            for (int u = tid; u < 48 * 8; u += 256) {
                int row = u >> 3, seg = u & 7;
                unsigned short* dst = Cv + ((size_t)bI * EE + (m0 - 384) + row) * NTOK + n0 + seg * 8;
                *(u16x8*)dst = *(const u16x8*)&Ts[row * 72 + seg * 8];
            }
        }
    }
}

// ---------------- MFMA bf16 attention, register-prefetch pipeline (R11/R13 exact) ----------------
__global__ __launch_bounds__(256) void attn_k2(const unsigned short* __restrict__ qkT,
                                               const unsigned short* __restrict__ vF,
                                               unsigned short* __restrict__ oT)
{
    __shared__ unsigned short Ks[128 * 40];       // [tok][d pad 40]
    __shared__ unsigned short Vs[32 * 136];       // [d][tok pad 136]
    __shared__ unsigned short Ps[4 * 32 * 72];    // per-wave [q][tok(64) pad 72]

    int blk = blockIdx.x;
    int bhs = blk & 127;
    int qc  = blk >> 7;
    int b = bhs >> 5, h = (bhs >> 2) & 7, s = bhs & 3;
    int tid  = threadIdx.x;
    int wv   = tid >> 6;
    int lane = tid & 63;
    int l15 = lane & 15, l4 = lane >> 4;
    int q0 = qc * 128;
    int tokbase = s * 1024;

    const unsigned short* qkb = qkT + (size_t)b * NTOK * QKST;

    if (tid < 128) {
        u16x8 z = (u16x8)0;
        *(u16x8*)&Ks[tid * 40 + 24] = z;          // K cols 24..31
    } else {
        for (int v = tid - 128; v < 14 * 16; v += 128) {   // V rows 18..31
            int d = 18 + (v >> 4), seg = v & 15;
            unsigned short val = (d == 31) ? (unsigned short)0x3F80 : (unsigned short)0;
            u16x8 vv = (u16x8)val;
            *(u16x8*)&Vs[d * 136 + seg * 8] = vv;
        }
    }

    bf16x8 qf[2];
    #pragma unroll
    for (int ni = 0; ni < 2; ++ni) {
        u16x8 raw = *(const u16x8*)(qkb + (size_t)(tokbase + q0 + wv * 32 + ni * 16 + l15) * QKST
                                    + 24 * h + l4 * 8);
        if (l4 == 3) raw = (u16x8)0;
        qf[ni] = *(bf16x8*)&raw;
    }

    floatx4 oacc[2][2];
    #pragma unroll
    for (int i = 0; i < 2; ++i)
        #pragma unroll
        for (int j = 0; j < 2; ++j)
            oacc[i][j] = (floatx4){0.f, 0.f, 0.f, 0.f};

    unsigned short* Pw = &Ps[wv * 32 * 72];

    u16x8 preg[3];
    int vb = tid - 128;
    bool v3 = (vb < 32);
    if (tid < 128) {
        const unsigned short* src = qkb + (size_t)(tokbase + tid) * QKST + 192 + 24 * h;
        preg[0] = *(const u16x8*)&src[0];
        preg[1] = *(const u16x8*)&src[8];
        preg[2] = *(const u16x8*)&src[16];
    } else {
        const unsigned short* vbb = vF + (size_t)b * EE * NTOK + tokbase;
        #pragma unroll
        for (int u = 0; u < 3; ++u) {
            int idx = vb + u * 128;
            if (u < 2 || v3) {
                int d = idx >> 4, seg = idx & 15;
                preg[u] = *(const u16x8*)(vbb + (size_t)(h * 18 + d) * NTOK + seg * 8);
            }
        }
    }

    for (int c0 = 0; c0 < 1024; c0 += 128) {
        __syncthreads();
        if (tid < 128) {
            unsigned short* dk = &Ks[tid * 40];
            *(u16x8*)&dk[0]  = preg[0];
            *(u16x8*)&dk[8]  = preg[1];
            *(u16x8*)&dk[16] = preg[2];
        } else {
            #pragma unroll
            for (int u = 0; u < 3; ++u) {
                int idx = vb + u * 128;
                if (u < 2 || v3) {
                    int d = idx >> 4, seg = idx & 15;
                    *(u16x8*)&Vs[d * 136 + seg * 8] = preg[u];
                }
            }
        }
        int cn = c0 + 128;
        if (cn < 1024) {
            if (tid < 128) {
                const unsigned short* src = qkb + (size_t)(tokbase + cn + tid) * QKST + 192 + 24 * h;
                preg[0] = *(const u16x8*)&src[0];
                preg[1] = *(const u16x8*)&src[8];
                preg[2] = *(const u16x8*)&src[16];
            } else {
                const unsigned short* vbb = vF + (size_t)b * EE * NTOK + tokbase + cn;
                #pragma unroll
                for (int u = 0; u < 3; ++u) {
                    int idx = vb + u * 128;
                    if (u < 2 || v3) {
                        int d = idx >> 4, seg = idx & 15;
                        preg[u] = *(const u16x8*)(vbb + (size_t)(h * 18 + d) * NTOK + seg * 8);
                    }
                }
            }
        }
        __syncthreads();

        #pragma unroll
        for (int sub = 0; sub < 2; ++sub) {
            bf16x8 kf[4];
            #pragma unroll
            for (int mi = 0; mi < 4; ++mi)
                kf[mi] = *(const bf16x8*)&Ks[(sub * 64 + mi * 16 + l15) * 40 + l4 * 8];

            floatx4 sacc[4][2];
            #pragma unroll
            for (int mi = 0; mi < 4; ++mi)
                #pragma unroll
                for (int ni = 0; ni < 2; ++ni) {
                    floatx4 z = (floatx4){0.f, 0.f, 0.f, 0.f};
                    sacc[mi][ni] = __builtin_amdgcn_mfma_f32_16x16x32_bf16(kf[mi], qf[ni], z, 0, 0, 0);
                }

            #pragma unroll
            for (int mi = 0; mi < 4; ++mi)
                #pragma unroll
                for (int ni = 0; ni < 2; ++ni) {
                    int ql   = ni * 16 + l15;
                    int tokb = mi * 16 + l4 * 4;
                    unsigned int lo = pack_bf_trunc(exp2f(sacc[mi][ni][0]), exp2f(sacc[mi][ni][1]));
                    unsigned int hi = pack_bf_trunc(exp2f(sacc[mi][ni][2]), exp2f(sacc[mi][ni][3]));
                    uint2 pk = make_uint2(lo, hi);
                    *(uint2*)&Pw[ql * 72 + tokb] = pk;
                }

            #pragma unroll
            for (int ks = 0; ks < 2; ++ks) {
                bf16x8 pf[2], vf[2];
                pf[0] = *(const bf16x8*)&Pw[(     l15) * 72 + ks * 32 + l4 * 8];
                pf[1] = *(const bf16x8*)&Pw[(16 + l15) * 72 + ks * 32 + l4 * 8];
                vf[0] = *(const bf16x8*)&Vs[(     l15) * 136 + sub * 64 + ks * 32 + l4 * 8];
                vf[1] = *(const bf16x8*)&Vs[(16 + l15) * 136 + sub * 64 + ks * 32 + l4 * 8];
                #pragma unroll
                for (int mi = 0; mi < 2; ++mi)
                    #pragma unroll
                    for (int nd = 0; nd < 2; ++nd)
                        oacc[mi][nd] = __builtin_amdgcn_mfma_f32_16x16x32_bf16(pf[mi], vf[nd], oacc[mi][nd], 0, 0, 0);
            }
        }
    }

    float* fO = (float*)Pw;
    #pragma unroll
    for (int mi = 0; mi < 2; ++mi)
        #pragma unroll
        for (int r = 0; r < 4; ++r) {
            float lsum = __shfl(oacc[mi][1][r], (lane & 48) | 15, 64);
            float inv  = 1.f / lsum;
            int ql = mi * 16 + l4 * 4 + r;
            fO[ql * 33 + l15] = oacc[mi][0][r] * inv;
            if (l15 < 2) fO[ql * 33 + 16 + l15] = oacc[mi][1][r] * inv;
        }

    {
        int q = lane & 31, dh = lane >> 5;
        size_t rowi = (size_t)b * NTOK + tokbase + q0 + wv * 32 + q;
        unsigned short* orow = oT + rowi * 160 + h * 18;
        for (int i = dh; i < 9; i += 2) {
            float a  = fO[q * 33 + 2 * i];
            float bb = fO[q * 33 + 2 * i + 1];
            *(unsigned int*)&orow[2 * i] = (unsigned)f2bf(a) | ((unsigned)f2bf(bb) << 16);
        }
        if (h == 7) {
            u16x8 z = (u16x8)0;
            *(u16x8*)(oT + rowi * 160 + 144 + dh * 8) = z;
        }
    }
}

// ---------------- fold (bf16 cols) + masked residual ----------------
__global__ __launch_bounds__(256) void fold_k(const unsigned short* __restrict__ cols,
                                              const float* __restrict__ tprev,
                                              float* __restrict__ t)
{
    int idx = blockIdx.x * 256 + threadIdx.x;
    int w = idx & 63;
    int h = (idx >> 6) & 63;
    int c = (idx >> 12) & 31;
    int b = idx >> 17;
    const unsigned short* cb = cols + (size_t)b * DD * NTOK + (size_t)c * 9 * NTOK;
    float sum = 0.f;
    #pragma unroll
    for (int i = 0; i < 3; ++i) {
        int hs = h + 1 - i;
        if ((unsigned)hs < 64u) {
            #pragma unroll
            for (int j = 0; j < 3; ++j) {
                int ws_ = w + 1 - j;
                if ((unsigned)ws_ < 64u)
                    sum += bf2f(cb[(size_t)(i * 3 + j) * NTOK + hs * 64 + ws_]);
            }
        }
    }
    int ch = (h == 0 || h == 63) ? 2 : 3;
    int cw_ = (w == 0 || w == 63) ? 2 : 3;
    t[idx] = sum + (float)(ch * cw_) * tprev[idx];
}

// ---------------- conv3x3 + ELU + residual, 4-pixel register strips ----------------
__global__ __launch_bounds__(256) void conv_k(const float* __restrict__ t,
    const float* __restrict__ cw, const float* __restrict__ cbias,
    const float* __restrict__ x, float* __restrict__ out)
{
    __shared__ float wsh[CC * 9];
    int blk = blockIdx.x;
    int band = blk & 3, co = (blk >> 2) & 31, b = blk >> 7;
    int tid = threadIdx.x;
    for (int u = tid; u < CC * 9; u += 256) wsh[u] = cw[co * CC * 9 + u];
    __syncthreads();
    int h = band * 16 + (tid >> 4);
    int w0 = (tid & 15) << 2;
    const float* tb = t + (size_t)b * CC * 4096;
    float bias = cbias[co];
    float a0 = bias, a1 = bias, a2 = bias, a3 = bias;
    for (int ci = 0; ci < CC; ++ci) {
        const float* tc = tb + (size_t)ci * 4096;
        const float* wr = &wsh[ci * 9];
        #pragma unroll
        for (int i = 0; i < 3; ++i) {
            int hr = h + i - 1;
            if ((unsigned)hr < 64u) {
                const float* row = tc + hr * 64;
                float vl = (w0 > 0)  ? row[w0 - 1] : 0.f;
                float4 c4 = *(const float4*)&row[w0];
                float vr = (w0 < 60) ? row[w0 + 4] : 0.f;
                float wj0 = wr[i * 3], wj1 = wr[i * 3 + 1], wj2 = wr[i * 3 + 2];
                a0 = fmaf(wj0, vl,   a0); a0 = fmaf(wj1, c4.x, a0); a0 = fmaf(wj2, c4.y, a0);
                a1 = fmaf(wj0, c4.x, a1); a1 = fmaf(wj1, c4.y, a1); a1 = fmaf(wj2, c4.z, a1);
                a2 = fmaf(wj0, c4.y, a2); a2 = fmaf(wj1, c4.z, a2); a2 = fmaf(wj2, c4.w, a2);
                a3 = fmaf(wj0, c4.z, a3); a3 = fmaf(wj1, c4.w, a3); a3 = fmaf(wj2, vr,   a3);
            }
        }
    }
    size_t oidx = ((size_t)(b * CC + co) * 4096) + h * 64 + w0;
    float4 xin = *(const float4*)&x[oidx];
    float4 o;
    o.x = xin.x + ((a0 > 0.f) ? a0 : (__expf(a0) - 1.f));
    o.y = xin.y + ((a1 > 0.f) ? a1 : (__expf(a1) - 1.f));
    o.z = xin.z + ((a2 > 0.f) ? a2 : (__expf(a2) - 1.f));
    o.w = xin.w + ((a3 > 0.f) ? a3 : (__expf(a3) - 1.f));
    *(float4*)&out[oidx] = o;
}

extern "C" void kernel_launch(void* const* d_in, const int* in_sizes, int n_in,
                              void* d_out, int out_size, void* d_ws, size_t ws_size,
                              hipStream_t stream)
{
    const float* x    = (const float*)d_in[0];
    const float* ln_g = (const float*)d_in[1];
    const float* ln_b = (const float*)d_in[2];
    const float* cw   = (const float*)d_in[3];
    const float* cb   = (const float*)d_in[4];
    const float* wr[3]   = {(const float*)d_in[5],  (const float*)d_in[10], (const float*)d_in[15]};
    const float* br[3]   = {(const float*)d_in[6],  (const float*)d_in[11], (const float*)d_in[16]};
    const float* wqkv[3] = {(const float*)d_in[7],  (const float*)d_in[12], (const float*)d_in[17]};
    const float* we[3]   = {(const float*)d_in[8],  (const float*)d_in[13], (const float*)d_in[18]};
    const float* be[3]   = {(const float*)d_in[9],  (const float*)d_in[14], (const float*)d_in[19]};
    float* out = (float*)d_out;

    char* p = (char*)d_ws;
    unsigned short* cols_bf = (unsigned short*)p; p += (size_t)BN * DD * NTOK * 2; // 9.4 MB (emha out, bf16)
    unsigned short* colsT = (unsigned short*)p; p += (size_t)BN * NTOK * 288 * 2;  // 9.4 MB
    unsigned short* oT = colsT;           // alias: disjoint lifetimes
    unsigned short* xrT   = (unsigned short*)p; p += (size_t)BN * NTOK * 160 * 2;  // 5.2 MB
    unsigned short* qkT   = (unsigned short*)p; p += (size_t)BN * NTOK * QKST * 2; // 12.6 MB
    unsigned short* vF    = (unsigned short*)p; p += (size_t)BN * EE * NTOK * 2;   // 4.7 MB
    float* mu   = (float*)p;              p += (size_t)BN * NTOK * 4;
    float* rstd = (float*)p;              p += (size_t)BN * NTOK * 4;
    float* tA   = (float*)p;              p += (size_t)BN * CC * HH * WW * 4;
    float* tB   = (float*)p;              p += (size_t)BN * CC * HH * WW * 4;
    unsigned short* wg_bf   = (unsigned short*)p; p += (size_t)3 * EE * DD * 2;
    unsigned short* wqkv_bf = (unsigned short*)p; p += (size_t)3 * MQKV * 160 * 2;
    unsigned short* we_bf   = (unsigned short*)p; p += (size_t)3 * DD * 160 * 2;
    float* wgsum = (float*)p;             p += 3 * EE * 4;
    float* wbeta = (float*)p;             p += 3 * EE * 4;
    (void)in_sizes; (void)n_in; (void)out_size; (void)ws_size;

    setup_k<<<1533, 256, 0, stream>>>(wr[0], br[0], wr[1], br[1], wr[2], br[2], ln_g, ln_b,
                                      wqkv[0], wqkv[1], wqkv[2], we[0], we[1], we[2],
                                      wg_bf, wgsum, wbeta, wqkv_bf, we_bf);

    const float* tin = x;
    float* touts[3] = {tA, tB, tA};
    for (int l = 0; l < 3; ++l) {
        unfold_k<<<256, 256, 0, stream>>>(tin, colsT, mu, rstd);
        // gemm1: K=288, M=144 (NYB=3)  -> grid 768
        mgemm_k<288, 1, 3><<<768, 256, 0, stream>>>(
            wg_bf + (size_t)l * EE * DD, colsT, 288, xrT, nullptr,
            mu, rstd, wgsum + l * EE, wbeta + l * EE, nullptr);
        // gemm2: K=160, M=528 (NYB=11) -> grid 2816
        mgemm_k<160, 0, 11><<<2816, 256, 0, stream>>>(
            wqkv_bf + (size_t)l * MQKV * 160, xrT, 160, qkT, vF,
            nullptr, nullptr, nullptr, nullptr, nullptr);
        attn_k2<<<1024, 256, 0, stream>>>(qkT, vF, oT);
        // gemm3: K=160, M=288 (NYB=6)  -> grid 1536
        mgemm_k<160, 2, 6><<<1536, 256, 0, stream>>>(
            we_bf + (size_t)l * DD * 160, oT, 160, cols_bf, nullptr,
            nullptr, nullptr, nullptr, nullptr, be[l]);
        fold_k<<<2048, 256, 0, stream>>>(cols_bf, tin, touts[l]);
        tin = touts[l];
    }
    conv_k<<<512, 256, 0, stream>>>(tA, cw, cb, x, out);
}